// Round 1
// baseline (307.238 us; speedup 1.0000x reference)
//
#include <hip/hip_runtime.h>
#include <hip/hip_bf16.h>

typedef __bf16 bf16_t;
typedef __bf16 bf16x8 __attribute__((ext_vector_type(8)));
typedef float f32x4 __attribute__((ext_vector_type(4)));

// ---------------------------------------------------------------------------
// fp32 -> bf16 cast kernel (memory-bound; 8 elems/thread, 16B stores)
// ---------------------------------------------------------------------------
__global__ __launch_bounds__(256) void cast_f32_to_bf16(
    const float* __restrict__ in, bf16_t* __restrict__ out, int n8) {
  int i = blockIdx.x * blockDim.x + threadIdx.x;
  if (i < n8) {
    const float4* in4 = (const float4*)in;
    float4 f0 = in4[2 * i];
    float4 f1 = in4[2 * i + 1];
    bf16x8 o;
    o[0] = (bf16_t)f0.x; o[1] = (bf16_t)f0.y;
    o[2] = (bf16_t)f0.z; o[3] = (bf16_t)f0.w;
    o[4] = (bf16_t)f1.x; o[5] = (bf16_t)f1.y;
    o[6] = (bf16_t)f1.z; o[7] = (bf16_t)f1.w;
    ((bf16x8*)out)[i] = o;
  }
}

// ---------------------------------------------------------------------------
// async global->LDS, 16B per lane. LDS dest = wave-uniform base + lane*16.
// ---------------------------------------------------------------------------
__device__ __forceinline__ void gload_lds16(const bf16_t* g, bf16_t* l) {
  __builtin_amdgcn_global_load_lds(
      (const __attribute__((address_space(1))) void*)g,
      (__attribute__((address_space(3))) void*)l,
      16, 0, 0);
}

// ---------------------------------------------------------------------------
// C[M,N] = A[M,K] * B[N,K]^T + bias[N], optional fused swish-poly.
// m97 structure: 128x128 tile, BK=32, 4 waves (2x2), 64x64 per wave,
// 4x4 mfma_f32_16x16x32_bf16 accumulators.
// SWISH=true  -> Cout is bf16* (stores swish(h))
// SWISH=false -> Cout is float* (stores h)
// Requires: M%128==0, N%128==0, K%32==0.
// ---------------------------------------------------------------------------
template <bool SWISH>
__global__ __launch_bounds__(256) void gemm_bt(
    const bf16_t* __restrict__ A, const bf16_t* __restrict__ B,
    const float* __restrict__ bias, void* __restrict__ Cout,
    int M, int N, int K) {
  const int tid  = threadIdx.x;
  const int wave = tid >> 6;
  const int lane = tid & 63;
  const int tileM = blockIdx.y << 7;
  const int tileN = blockIdx.x << 7;

  __shared__ __align__(16) bf16_t sA[128 * 32];
  __shared__ __align__(16) bf16_t sB[128 * 32];

  // ---- staging addresses (wave w stages rows [w*16,w*16+16) and +64) ----
  const int sRow = (wave << 4) + (lane >> 2);  // 0..63
  const int sCol = (lane & 3) << 3;            // 0,8,16,24
  const bf16_t* gA0 = A + (size_t)(tileM + sRow) * K + sCol;
  const bf16_t* gA1 = gA0 + (size_t)64 * K;
  const bf16_t* gB0 = B + (size_t)(tileN + sRow) * K + sCol;
  const bf16_t* gB1 = gB0 + (size_t)64 * K;
  bf16_t* lA0 = sA + (wave << 4) * 32;  // wave-uniform base
  bf16_t* lA1 = lA0 + 64 * 32;
  bf16_t* lB0 = sB + (wave << 4) * 32;
  bf16_t* lB1 = lB0 + 64 * 32;

  // ---- fragment read pointers (fixed across K loop) ----
  const int wr = wave >> 1;       // wave row (0..1)
  const int wc = wave & 1;        // wave col (0..1)
  const int fRow = lane & 15;
  const int fK = (lane >> 4) << 3;  // 0,8,16,24
  const bf16x8* pA[4];
  const bf16x8* pB[4];
#pragma unroll
  for (int i = 0; i < 4; ++i) {
    pA[i] = (const bf16x8*)(sA + ((wr * 64 + i * 16 + fRow) * 32 + fK));
    pB[i] = (const bf16x8*)(sB + ((wc * 64 + i * 16 + fRow) * 32 + fK));
  }

  f32x4 acc[4][4] = {};

  for (int kt = 0; kt < K; kt += 32) {
    gload_lds16(gA0 + kt, lA0);
    gload_lds16(gA1 + kt, lA1);
    gload_lds16(gB0 + kt, lB0);
    gload_lds16(gB1 + kt, lB1);
    __syncthreads();  // compiler drains vmcnt before barrier

    bf16x8 af[4], bfr[4];
#pragma unroll
    for (int i = 0; i < 4; ++i) {
      af[i] = *pA[i];
      bfr[i] = *pB[i];
    }
#pragma unroll
    for (int i = 0; i < 4; ++i)
#pragma unroll
      for (int j = 0; j < 4; ++j)
        acc[i][j] = __builtin_amdgcn_mfma_f32_16x16x32_bf16(
            af[i], bfr[j], acc[i][j], 0, 0, 0);
    __syncthreads();  // protect LDS before next stage
  }

  // ---- epilogue: C/D layout col = lane&15, row = (lane>>4)*4 + reg ----
  const int cRow0 = tileM + wr * 64 + ((lane >> 4) << 2);
  const int cCol0 = tileN + wc * 64 + (lane & 15);
#pragma unroll
  for (int j = 0; j < 4; ++j) {
    const int col = cCol0 + j * 16;
    const float bv = bias[col];
#pragma unroll
    for (int i = 0; i < 4; ++i) {
      const int row = cRow0 + i * 16;
#pragma unroll
      for (int r = 0; r < 4; ++r) {
        float h = acc[i][j][r] + bv;
        if constexpr (SWISH) {
          // swish via poly sigmoid: h * (0.5 + 0.25h - 0.0208 h^3)
          float h3 = h * h * h;
          float sw = h * (0.5f + 0.25f * h - 0.0208f * h3);
          ((bf16_t*)Cout)[(size_t)(row + r) * N + col] = (bf16_t)sw;
        } else {
          ((float*)Cout)[(size_t)(row + r) * N + col] = h;
        }
      }
    }
  }
}

// ---------------------------------------------------------------------------
// launch
// ---------------------------------------------------------------------------
extern "C" void kernel_launch(void* const* d_in, const int* in_sizes, int n_in,
                              void* d_out, int out_size, void* d_ws,
                              size_t ws_size, hipStream_t stream) {
  const float* X  = (const float*)d_in[0];  // [B,S,D] = [M,D]
  const float* W1 = (const float*)d_in[1];  // [F,D]
  const float* b1 = (const float*)d_in[2];  // [F]
  const float* W2 = (const float*)d_in[3];  // [D,F]
  const float* b2 = (const float*)d_in[4];  // [D]
  float* out = (float*)d_out;               // [M,D]

  const int F = in_sizes[2];            // 4096
  const int D = in_sizes[4];            // 1024
  const int M = in_sizes[0] / D;        // 8192

  // workspace layout (bf16): Xb[M*D] | W1b[F*D] | W2b[D*F] | SW[M*F]
  bf16_t* Xb  = (bf16_t*)d_ws;
  bf16_t* W1b = Xb + (size_t)M * D;
  bf16_t* W2b = W1b + (size_t)F * D;
  bf16_t* SW  = W2b + (size_t)D * F;

  const int nX = (M * D) / 8, nW1 = (F * D) / 8, nW2 = (D * F) / 8;
  cast_f32_to_bf16<<<(nX + 255) / 256, 256, 0, stream>>>(X, Xb, nX);
  cast_f32_to_bf16<<<(nW1 + 255) / 256, 256, 0, stream>>>(W1, W1b, nW1);
  cast_f32_to_bf16<<<(nW2 + 255) / 256, 256, 0, stream>>>(W2, W2b, nW2);

  // GEMM1: SW[M,F] = swish(Xb[M,D] @ W1b[F,D]^T + b1)   (bf16 out)
  gemm_bt<true><<<dim3(F / 128, M / 128), 256, 0, stream>>>(
      Xb, W1b, b1, (void*)SW, M, F, D);

  // GEMM2: out[M,D] = SW[M,F] @ W2b[D,F]^T + b2         (fp32 out)
  gemm_bt<false><<<dim3(D / 128, M / 128), 256, 0, stream>>>(
      SW, W2b, b2, (void*)out, M, D, F);
}

// Round 2
// 266.000 us; speedup vs baseline: 1.1550x; 1.1550x over previous
//
#include <hip/hip_runtime.h>
#include <hip/hip_bf16.h>

typedef __bf16 bf16_t;
typedef __bf16 bf16x8 __attribute__((ext_vector_type(8)));
typedef float f32x4 __attribute__((ext_vector_type(4)));

// ---------------------------------------------------------------------------
// fused fp32 -> bf16 cast for 3 arrays (one launch; memory-bound)
// ---------------------------------------------------------------------------
__global__ __launch_bounds__(256) void cast3_f32_to_bf16(
    const float* __restrict__ a, bf16_t* __restrict__ ao, int na8,
    const float* __restrict__ b, bf16_t* __restrict__ bo, int nb8,
    const float* __restrict__ c, bf16_t* __restrict__ co, int nc8) {
  int i = blockIdx.x * blockDim.x + threadIdx.x;
  const float* in;
  bf16_t* out;
  int j;
  if (i < na8) {
    in = a; out = ao; j = i;
  } else if (i < na8 + nb8) {
    in = b; out = bo; j = i - na8;
  } else if (i < na8 + nb8 + nc8) {
    in = c; out = co; j = i - na8 - nb8;
  } else {
    return;
  }
  const float4* in4 = (const float4*)in;
  float4 f0 = in4[2 * j];
  float4 f1 = in4[2 * j + 1];
  bf16x8 o;
  o[0] = (bf16_t)f0.x; o[1] = (bf16_t)f0.y;
  o[2] = (bf16_t)f0.z; o[3] = (bf16_t)f0.w;
  o[4] = (bf16_t)f1.x; o[5] = (bf16_t)f1.y;
  o[6] = (bf16_t)f1.z; o[7] = (bf16_t)f1.w;
  ((bf16x8*)out)[j] = o;
}

// ---------------------------------------------------------------------------
// async global->LDS, 16B per lane. LDS dest = wave-uniform base + lane*16.
// ---------------------------------------------------------------------------
__device__ __forceinline__ void gload_lds16(const bf16_t* g, bf16_t* l) {
  __builtin_amdgcn_global_load_lds(
      (const __attribute__((address_space(1))) void*)g,
      (__attribute__((address_space(3))) void*)l,
      16, 0, 0);
}

// ---------------------------------------------------------------------------
// C[M,N] = A[M,K] * B[N,K]^T + bias[N], optional fused swish-poly.
// 128x128 tile, BK=64, 4 waves (2x2), 64x64 per wave, 4x4 16x16x32 MFMA.
// LDS rows are 128B (32 banks); global chunk (l&7)^(l>>3) is staged at LDS
// chunk (l&7) -> read-side physical chunk = logical ^ (row&7): conflict-free.
// 1D grid with XCD-aware swizzle: bid%8 = XCD (round-robin assumption),
// each XCD gets a px*py tile patch for L2 locality.
// SWISH=true -> Cout bf16 (swish(h)); SWISH=false -> Cout fp32 (h).
// Requires: M%128==0, N%128==0, K%64==0.
// ---------------------------------------------------------------------------
template <bool SWISH>
__global__ __launch_bounds__(256) void gemm_bt(
    const bf16_t* __restrict__ A, const bf16_t* __restrict__ B,
    const float* __restrict__ bias, void* __restrict__ Cout,
    int M, int N, int K, int XW, int px, int py) {
  const int tid  = threadIdx.x;
  const int wave = tid >> 6;
  const int lane = tid & 63;

  // ---- XCD-aware block swizzle ----
  const int bid = blockIdx.x;
  const int xcd = bid & 7;
  const int idx = bid >> 3;
  const int cx = xcd % XW;
  const int cy = xcd / XW;
  const int bx = cx * px + idx % px;
  const int by = cy * py + idx / px;
  const int tileM = by << 7;
  const int tileN = bx << 7;

  __shared__ __align__(16) bf16_t sA[128 * 64];
  __shared__ __align__(16) bf16_t sB[128 * 64];

  // ---- staging: 4 rounds of 32 rows each (8 rows/wave), 16B/lane ----
  // lane -> local row (l>>3), LDS chunk (l&7); fetches GLOBAL chunk (l&7)^(l>>3)
  const int srow = (wave << 3) + (lane >> 3);          // 0..31 within round
  const int gcol = (((lane & 7) ^ (lane >> 3)) << 3);  // swizzled global col
  const bf16_t* gA = A + (size_t)(tileM + srow) * K + gcol;
  const bf16_t* gB = B + (size_t)(tileN + srow) * K + gcol;
  bf16_t* lA = sA + (size_t)(wave << 3) * 64;  // wave-uniform base (+r*32 rows)
  bf16_t* lB = sB + (size_t)(wave << 3) * 64;

  // ---- fragment read pointers ----
  const int wr = wave >> 1;  // wave row (0..1)
  const int wc = wave & 1;   // wave col (0..1)
  const int fRow = lane & 15;
  const int c0 = lane >> 4;        // logical 16B chunk for kstep 0 (0..3)
  const int swz = lane & 7;        // row&7 of this lane's fragment rows
  const int p0 = c0 ^ swz;         // physical chunk, kstep 0
  const int d1 = (((p0 ^ 4) - p0) << 3);  // elem delta to kstep-1 chunk
  const bf16x8* pA[4];
  const bf16x8* pB[4];
#pragma unroll
  for (int i = 0; i < 4; ++i) {
    const int lrA = wr * 64 + i * 16 + fRow;
    const int lrB = wc * 64 + i * 16 + fRow;
    pA[i] = (const bf16x8*)(sA + lrA * 64 + p0 * 8);
    pB[i] = (const bf16x8*)(sB + lrB * 64 + p0 * 8);
  }

  f32x4 acc[4][4] = {};

  for (int kt = 0; kt < K; kt += 64) {
#pragma unroll
    for (int r = 0; r < 4; ++r) {
      gload_lds16(gA + kt + (size_t)(r * 32) * K, lA + r * 32 * 64);
      gload_lds16(gB + kt + (size_t)(r * 32) * K, lB + r * 32 * 64);
    }
    __syncthreads();

    bf16x8 a0[4], b0[4];
#pragma unroll
    for (int i = 0; i < 4; ++i) {
      a0[i] = *pA[i];
      b0[i] = *pB[i];
    }
#pragma unroll
    for (int i = 0; i < 4; ++i)
#pragma unroll
      for (int j = 0; j < 4; ++j)
        acc[i][j] = __builtin_amdgcn_mfma_f32_16x16x32_bf16(
            a0[i], b0[j], acc[i][j], 0, 0, 0);

    bf16x8 a1[4], b1[4];
#pragma unroll
    for (int i = 0; i < 4; ++i) {
      a1[i] = *(const bf16x8*)((const bf16_t*)pA[i] + d1);
      b1[i] = *(const bf16x8*)((const bf16_t*)pB[i] + d1);
    }
#pragma unroll
    for (int i = 0; i < 4; ++i)
#pragma unroll
      for (int j = 0; j < 4; ++j)
        acc[i][j] = __builtin_amdgcn_mfma_f32_16x16x32_bf16(
            a1[i], b1[j], acc[i][j], 0, 0, 0);
    __syncthreads();
  }

  // ---- epilogue: C/D layout col = lane&15, row = (lane>>4)*4 + reg ----
  const int cRow0 = tileM + wr * 64 + ((lane >> 4) << 2);
  const int cCol0 = tileN + wc * 64 + (lane & 15);
#pragma unroll
  for (int j = 0; j < 4; ++j) {
    const int col = cCol0 + j * 16;
    const float bv = bias[col];
#pragma unroll
    for (int i = 0; i < 4; ++i) {
      const int row = cRow0 + i * 16;
#pragma unroll
      for (int r = 0; r < 4; ++r) {
        float h = acc[i][j][r] + bv;
        if constexpr (SWISH) {
          float h3 = h * h * h;
          float sw = h * (0.5f + 0.25f * h - 0.0208f * h3);
          ((bf16_t*)Cout)[(size_t)(row + r) * N + col] = (bf16_t)sw;
        } else {
          ((float*)Cout)[(size_t)(row + r) * N + col] = h;
        }
      }
    }
  }
}

// ---------------------------------------------------------------------------
// launch
// ---------------------------------------------------------------------------
extern "C" void kernel_launch(void* const* d_in, const int* in_sizes, int n_in,
                              void* d_out, int out_size, void* d_ws,
                              size_t ws_size, hipStream_t stream) {
  const float* X  = (const float*)d_in[0];  // [B,S,D] = [M,D]
  const float* W1 = (const float*)d_in[1];  // [F,D]
  const float* b1 = (const float*)d_in[2];  // [F]
  const float* W2 = (const float*)d_in[3];  // [D,F]
  const float* b2 = (const float*)d_in[4];  // [D]
  float* out = (float*)d_out;               // [M,D]

  const int F = in_sizes[2];      // 4096
  const int D = in_sizes[4];      // 1024
  const int M = in_sizes[0] / D;  // 8192

  // workspace layout (bf16): Xb[M*D] | W1b[F*D] | W2b[D*F] | SW[M*F]
  bf16_t* Xb  = (bf16_t*)d_ws;
  bf16_t* W1b = Xb + (size_t)M * D;
  bf16_t* W2b = W1b + (size_t)F * D;
  bf16_t* SW  = W2b + (size_t)D * F;

  const int nX = (M * D) / 8, nW1 = (F * D) / 8, nW2 = (D * F) / 8;
  const int nTot = nX + nW1 + nW2;
  cast3_f32_to_bf16<<<(nTot + 255) / 256, 256, 0, stream>>>(
      X, Xb, nX, W1, W1b, nW1, W2, W2b, nW2);

  // GEMM1: SW[M,F] = swish(Xb[M,D] @ W1b[F,D]^T + b1)   (bf16 out)
  // grid tiles: gx = F/128 = 32, gy = M/128 = 64; XCDs as 2x4 -> 16x16 patch
  {
    const int gx = F / 128, gy = M / 128;
    const int XW = 2, XH = 4;
    const int px = gx / XW, py = gy / XH;
    gemm_bt<true><<<gx * gy, 256, 0, stream>>>(
        Xb, W1b, b1, (void*)SW, M, F, D, XW, px, py);
  }

  // GEMM2: out[M,D] = SW[M,F] @ W2b[D,F]^T + b2         (fp32 out)
  // grid tiles: gx = D/128 = 8, gy = M/128 = 64; XCDs as 1x8 -> 8x8 patch
  {
    const int gx = D / 128, gy = M / 128;
    const int XW = 1, XH = 8;
    const int px = gx / XW, py = gy / XH;
    gemm_bt<false><<<gx * gy, 256, 0, stream>>>(
        SW, W2b, b2, (void*)out, M, D, F, XW, px, py);
  }
}